// Round 21
// baseline (104.958 us; speedup 1.0000x reference)
//
#include <hip/hip_runtime.h>
#include <hip/hip_bf16.h>
#include <math.h>

#define NB 32768          // B
#define NSEG 65536        // 2*B
#define NRF 11            // read features
#define NIF 9             // info features
#define K1_BLOCKS 4096    // phi blocks in the fused dispatch

typedef __attribute__((ext_vector_type(8))) short bf16x8;
typedef __attribute__((ext_vector_type(4))) float f32x4;
typedef __attribute__((ext_vector_type(4))) unsigned u32x4;

__device__ __forceinline__ short to_bf(float f) {
    __hip_bfloat16 h = __float2bfloat16(f);   // RNE
    return *reinterpret_cast<short*>(&h);
}
__device__ __forceinline__ float bf2f(short s) {
    __hip_bfloat16 h = *reinterpret_cast<__hip_bfloat16*>(&s);
    return __bfloat162float(h);
}
// HW packed f32->bf16 RNE: lo -> D[15:0], hi -> D[31:16].
__device__ __forceinline__ unsigned cvt_pk_bf16(float lo, float hi) {
    unsigned r;
    asm("v_cvt_pk_bf16_f32 %0, %1, %2" : "=v"(r) : "v"(lo), "v"(hi));
    return r;
}

// ---------------------------------------------------------------------------
// K0: one-time weight prep into ws. (unchanged)
// ---------------------------------------------------------------------------
__global__ __launch_bounds__(256) void k0_prep(
    const float* __restrict__ rw0, const float* __restrict__ rw1,
    const float* __restrict__ pw0, const float* __restrict__ pw1,
    short* __restrict__ w0th, short* __restrict__ w0tl,
    short* __restrict__ w1th, short* __restrict__ w1tl,
    short* __restrict__ p_w0t, short* __restrict__ p_w1t)
{
    const int idx = blockIdx.x * 256 + threadIdx.x;
    if (idx < 192 * 128) {
        const int k = idx >> 7, col = idx & 127;      // rw0[k][col]
        const float v = rw0[idx];
        const short hi = to_bf(v);
        const short lo = to_bf(v - bf2f(hi));
        w0th[col * 192 + k] = hi;
        w0tl[col * 192 + k] = lo;
    }
    if (idx < 128 * 64) {
        const int k = idx >> 6, col = idx & 63;       // rw1[k][col]
        const float v = rw1[idx];
        const short hi = to_bf(v);
        const short lo = to_bf(v - bf2f(hi));
        w1th[col * 128 + k] = hi;
        w1tl[col * 128 + k] = lo;
    }
    if (idx < 64 * 16) {
        const int col = idx >> 4, k = idx & 15;
        p_w0t[idx] = (k < NRF) ? to_bf(pw0[k * 64 + col]) : (short)0;
    }
    if (idx < 64 * 64) {
        const int col = idx >> 6, kp = idx & 63;
        const int c = kp >> 5, rem = kp & 31;
        const int lgi = rem >> 3, e = rem & 7;
        const int k = 32 * c + 16 * (e >> 2) + 4 * lgi + (e & 3);  // sigma(kp)
        p_w1t[idx] = to_bf(pw1[k * 64 + col]);
    }
}

// ---------------------------------------------------------------------------
// X-fragment load straight from global, segment-clamped row. (unchanged)
// ---------------------------------------------------------------------------
__device__ __forceinline__ bf16x8 load_xfrag(
    const float* __restrict__ reads, int e0v, int cnt, int tt, int lr, int lg)
{
    int rrow = tt * 16 + lr;
    rrow = (rrow < cnt) ? rrow : (cnt - 1);
    const size_t gbase = (size_t)(e0v + rrow) * NRF;
    bf16x8 xb = {0, 0, 0, 0, 0, 0, 0, 0};
    if (lg == 0) {
        const f32x4 x0 = *(const f32x4*)(reads + gbase);
        const f32x4 x1 = *(const f32x4*)(reads + gbase + 4);
        union { u32x4 u; bf16x8 s; } t;
        t.u = (u32x4){ cvt_pk_bf16(x0[0], x0[1]), cvt_pk_bf16(x0[2], x0[3]),
                       cvt_pk_bf16(x1[0], x1[1]), cvt_pk_bf16(x1[2], x1[3]) };
        xb = t.s;
    } else if (lg == 1) {
        const float xa = reads[gbase + 8];
        const float xbv = reads[gbase + 9];
        const float xc = reads[gbase + 10];
        union { u32x4 u; bf16x8 s; } t;
        t.u = (u32x4){ cvt_pk_bf16(xa, xbv), cvt_pk_bf16(xc, 0.f), 0u, 0u };
        xb = t.s;
    }
    return xb;
}

// ---------------------------------------------------------------------------
// K12 fused v4: round-18 dual-chain phi body, but at __launch_bounds__(256,2)
// — 256-VGPR budget so the 2x in-flight state FITS (rounds 13/18/19 spilled
// only because of the 128-reg cap). 8 waves/CU x 2 chains = 16 concurrent
// chains vs 12 at the old bound. Omega path unchanged.
// ---------------------------------------------------------------------------
__global__ __launch_bounds__(256, 2) void k12_fused(
    const float* __restrict__ reads,
    const int* __restrict__ endi,
    const short* __restrict__ p_w0t, const short* __restrict__ p_w1t,
    const float* __restrict__ b0, const float* __restrict__ b1,
    float* __restrict__ means,
    const float* __restrict__ info,
    const float* __restrict__ ow0, const float* __restrict__ ob0,
    const float* __restrict__ ow1, const float* __restrict__ ob1,
    float* __restrict__ om)
{
    __shared__ float hbuf[4][64];     // K2 path only (1 KB)

    const int tid  = threadIdx.x;
    const int lane = tid & 63;
    const int w    = tid >> 6;

    if (blockIdx.x < K1_BLOCKS) {
        // ================== phi body (dual-chain, 256-reg budget) ==========
        const int lg   = lane >> 4;       // 0..3
        const int lr   = lane & 15;       // 0..15
        const int k0   = lg * 8;
        const int s0   = blockIdx.x * 16;

        bf16x8 aW0[4];
#pragma unroll
        for (int nt = 0; nt < 4; ++nt) {
            bf16x8 z = {0, 0, 0, 0, 0, 0, 0, 0};
            if (lg < 2) z = *(const bf16x8*)&p_w0t[(nt * 16 + lr) * 16 + k0];
            aW0[nt] = z;
        }
        bf16x8 bW1[4][2];
#pragma unroll
        for (int nt = 0; nt < 4; ++nt)
#pragma unroll
            for (int ks = 0; ks < 2; ++ks)
                bW1[nt][ks] = *(const bf16x8*)&p_w1t[(nt * 16 + lr) * 64 + ks * 32 + k0];

        f32x4 cbias0[4];
#pragma unroll
        for (int nt = 0; nt < 4; ++nt)
#pragma unroll
            for (int q = 0; q < 4; ++q) cbias0[nt][q] = b0[nt * 16 + 4 * lg + q];
        float bias1v[4];                  // L2 bias as VALU add
#pragma unroll
        for (int nt = 0; nt < 4; ++nt) bias1v[nt] = b1[nt * 16 + lr];

        for (int qp = 0; qp < 2; ++qp) {
            const int sA = s0 + qp * 8 + w;
            const int sB = sA + 4;
            const int e1A = endi[sA];
            const int e0A = (sA == 0) ? 0 : endi[sA - 1];
            const int e1B = endi[sB];
            const int e0B = endi[sB - 1];          // sB >= 4, always valid
            const int cntA = e1A - e0A, cntB = e1B - e0B;
            const int ntlA = (cntA + 15) >> 4, ntlB = (cntB + 15) >> 4;
            const int ntl  = (ntlA > ntlB) ? ntlA : ntlB;   // 1 or 2
            float ssA[4] = {0.f, 0.f, 0.f, 0.f};
            float ssB[4] = {0.f, 0.f, 0.f, 0.f};

            bf16x8 xbA = load_xfrag(reads, e0A, cntA, 0, lr, lg);
            bf16x8 xbB = load_xfrag(reads, e0B, cntB, 0, lr, lg);

            for (int tt = 0; tt < ntl; ++tt) {
                bf16x8 xbAn = {0, 0, 0, 0, 0, 0, 0, 0};
                bf16x8 xbBn = {0, 0, 0, 0, 0, 0, 0, 0};
                if (tt + 1 < ntl) {
                    xbAn = load_xfrag(reads, e0A, cntA, tt + 1, lr, lg);
                    xbBn = load_xfrag(reads, e0B, cntB, tt + 1, lr, lg);
                }

                // layer 1: both chains back-to-back
                f32x4 dA[4], dB[4];
#pragma unroll
                for (int nt = 0; nt < 4; ++nt)
                    dA[nt] = __builtin_amdgcn_mfma_f32_16x16x32_bf16(aW0[nt], xbA, cbias0[nt], 0, 0, 0);
#pragma unroll
                for (int nt = 0; nt < 4; ++nt)
                    dB[nt] = __builtin_amdgcn_mfma_f32_16x16x32_bf16(aW0[nt], xbB, cbias0[nt], 0, 0, 0);

                // relu + in-register repack, both chains
                union { u32x4 u; bf16x8 s; } a0A, a1A, a0B, a1B;
                a0A.u = (u32x4){ cvt_pk_bf16(fmaxf(dA[0][0],0.f), fmaxf(dA[0][1],0.f)),
                                 cvt_pk_bf16(fmaxf(dA[0][2],0.f), fmaxf(dA[0][3],0.f)),
                                 cvt_pk_bf16(fmaxf(dA[1][0],0.f), fmaxf(dA[1][1],0.f)),
                                 cvt_pk_bf16(fmaxf(dA[1][2],0.f), fmaxf(dA[1][3],0.f)) };
                a1A.u = (u32x4){ cvt_pk_bf16(fmaxf(dA[2][0],0.f), fmaxf(dA[2][1],0.f)),
                                 cvt_pk_bf16(fmaxf(dA[2][2],0.f), fmaxf(dA[2][3],0.f)),
                                 cvt_pk_bf16(fmaxf(dA[3][0],0.f), fmaxf(dA[3][1],0.f)),
                                 cvt_pk_bf16(fmaxf(dA[3][2],0.f), fmaxf(dA[3][3],0.f)) };
                a0B.u = (u32x4){ cvt_pk_bf16(fmaxf(dB[0][0],0.f), fmaxf(dB[0][1],0.f)),
                                 cvt_pk_bf16(fmaxf(dB[0][2],0.f), fmaxf(dB[0][3],0.f)),
                                 cvt_pk_bf16(fmaxf(dB[1][0],0.f), fmaxf(dB[1][1],0.f)),
                                 cvt_pk_bf16(fmaxf(dB[1][2],0.f), fmaxf(dB[1][3],0.f)) };
                a1B.u = (u32x4){ cvt_pk_bf16(fmaxf(dB[2][0],0.f), fmaxf(dB[2][1],0.f)),
                                 cvt_pk_bf16(fmaxf(dB[2][2],0.f), fmaxf(dB[2][3],0.f)),
                                 cvt_pk_bf16(fmaxf(dB[3][0],0.f), fmaxf(dB[3][1],0.f)),
                                 cvt_pk_bf16(fmaxf(dB[3][2],0.f), fmaxf(dB[3][3],0.f)) };

                // layer 2: both chains
                f32x4 oA[4], oB[4];
                const f32x4 zf = {0.f, 0.f, 0.f, 0.f};
#pragma unroll
                for (int nt = 0; nt < 4; ++nt) {
                    f32x4 t = __builtin_amdgcn_mfma_f32_16x16x32_bf16(a0A.s, bW1[nt][0], zf, 0, 0, 0);
                    oA[nt]  = __builtin_amdgcn_mfma_f32_16x16x32_bf16(a1A.s, bW1[nt][1], t, 0, 0, 0);
                }
#pragma unroll
                for (int nt = 0; nt < 4; ++nt) {
                    f32x4 t = __builtin_amdgcn_mfma_f32_16x16x32_bf16(a0B.s, bW1[nt][0], zf, 0, 0, 0);
                    oB[nt]  = __builtin_amdgcn_mfma_f32_16x16x32_bf16(a1B.s, bW1[nt][1], t, 0, 0, 0);
                }

                // sigmoid + row mask, both chains
                const int rowg = tt * 16 + 4 * lg;
#pragma unroll
                for (int nt = 0; nt < 4; ++nt) {
                    const float bv = bias1v[nt];
                    float sa = ssA[nt], sb = ssB[nt];
#pragma unroll
                    for (int q2 = 0; q2 < 4; ++q2) {
                        const float pA = __builtin_amdgcn_rcpf(1.f + __expf(-(oA[nt][q2] + bv)));
                        const float pB = __builtin_amdgcn_rcpf(1.f + __expf(-(oB[nt][q2] + bv)));
                        sa += (rowg + q2 < cntA) ? pA : 0.f;
                        sb += (rowg + q2 < cntB) ? pB : 0.f;
                    }
                    ssA[nt] = sa;
                    ssB[nt] = sb;
                }
                xbA = xbAn;
                xbB = xbBn;
            }
            // cross-lane reductions + stores
#pragma unroll
            for (int nt = 0; nt < 4; ++nt) {
                ssA[nt] += __shfl_xor(ssA[nt], 16);
                ssA[nt] += __shfl_xor(ssA[nt], 32);
                ssB[nt] += __shfl_xor(ssB[nt], 16);
                ssB[nt] += __shfl_xor(ssB[nt], 32);
            }
            if (lg == 0) {
                const float invA = 1.f / (float)cntA;
                const float invB = 1.f / (float)cntB;
#pragma unroll
                for (int nt = 0; nt < 4; ++nt) {
                    means[(size_t)sA * 64 + nt * 16 + lr] = ssA[nt] * invA;
                    means[(size_t)sB * 64 + nt * 16 + lr] = ssB[nt] * invB;
                }
            }
        }
    } else {
        // ================== omega body (K2, unchanged) ======================
        const int wg = __builtin_amdgcn_readfirstlane(
            (int)((blockIdx.x - K1_BLOCKS) * 4 + w));

        float w0c[NIF];
#pragma unroll
        for (int k = 0; k < NIF; ++k) w0c[k] = ow0[k * 64 + lane];
        float w1c[64];
#pragma unroll
        for (int i = 0; i < 64; ++i) w1c[i] = ow1[i * 64 + lane];
        const float b0l = ob0[lane];
        const float b1l = ob1[lane];

        for (int i = 0; i < 8; ++i) {
            const int b = wg * 8 + i;
            const float* __restrict__ x = info + (size_t)b * NIF;
            float h = b0l;
#pragma unroll
            for (int k = 0; k < NIF; ++k) h = fmaf(x[k], w0c[k], h);
            h = fmaxf(h, 0.f);
            hbuf[w][lane] = h;
            float o = b1l;
            const float4* h4 = (const float4*)(&hbuf[w][0]);
#pragma unroll
            for (int q = 0; q < 16; ++q) {
                float4 hv = h4[q];
                o = fmaf(hv.x, w1c[4 * q + 0], o);
                o = fmaf(hv.y, w1c[4 * q + 1], o);
                o = fmaf(hv.z, w1c[4 * q + 2], o);
                o = fmaf(hv.w, w1c[4 * q + 3], o);
            }
            om[(size_t)b * 64 + lane] = 1.f / (1.f + __expf(-o));
        }
    }
}

// ---------------------------------------------------------------------------
// K3: rho MLP via split-bf16 MFMA (hh + lh + hl). (unchanged)
// ---------------------------------------------------------------------------
__global__ __launch_bounds__(256) void k3_rho_mfma(
    const float* __restrict__ means, const float* __restrict__ om,
    const int* __restrict__ endi,
    const short* __restrict__ w0th, const short* __restrict__ w0tl,
    const short* __restrict__ w1th, const short* __restrict__ w1tl,
    const float* __restrict__ rb0, const float* __restrict__ rb1,
    const float* __restrict__ rw2, const float* __restrict__ rb2,
    const float* __restrict__ cw0, const float* __restrict__ cb0,
    const float* __restrict__ cw1, const float* __restrict__ cb1,
    const float* __restrict__ cw2, const float* __restrict__ cb2,
    const float* __restrict__ max_logit,
    float* __restrict__ out)
{
    __shared__ __align__(16) char smemA[18432];
    __shared__ __align__(16) char smemB[34816];
    short (*XH)[72]  = (short(*)[72])smemA;
    short (*XL)[72]  = (short(*)[72])(smemA + 9216);
    short (*HH)[136] = (short(*)[136])smemB;
    short (*HL)[136] = (short(*)[136])(smemB + 17408);
    float (*h2T)[68] = (float(*)[68])smemA;

    const int tid  = threadIdx.x;
    const int lane = tid & 63;
    const int w    = tid >> 6;
    const int lg   = lane >> 4;
    const int lr   = lane & 15;
    const int k0   = lg * 8;
    const int b0i  = blockIdx.x * 64;

    const int wbase = w * 32;
    float bias0[2];
#pragma unroll
    for (int nt = 0; nt < 2; ++nt) bias0[nt] = rb0[wbase + nt * 16 + lr];

    f32x4 acc[4][2];
#pragma unroll
    for (int rt = 0; rt < 4; ++rt)
#pragma unroll
        for (int nt = 0; nt < 2; ++nt) acc[rt][nt] = (f32x4){0.f, 0.f, 0.f, 0.f};

    for (int c = 0; c < 3; ++c) {
        const float* __restrict__ src =
            (c == 0) ? means + (size_t)b0i * 64 :
            (c == 1) ? means + (size_t)(NB + b0i) * 64 :
                       om    + (size_t)b0i * 64;
        __syncthreads();
        for (int idx = tid; idx < 64 * 64; idx += 256) {
            const int row = idx >> 6, col = idx & 63;
            const float v = src[(size_t)row * 64 + col];
            const short hi = to_bf(v);
            const short lo = to_bf(v - bf2f(hi));
            XH[row][col] = hi;
            XL[row][col] = lo;
        }
        __syncthreads();

#pragma unroll
        for (int ks = 0; ks < 2; ++ks) {
            const int koff = c * 64 + ks * 32 + k0;
            bf16x8 Bh[2], Bl[2];
#pragma unroll
            for (int nt = 0; nt < 2; ++nt) {
                const int col = wbase + nt * 16 + lr;
                Bh[nt] = *(const bf16x8*)&w0th[(size_t)col * 192 + koff];
                Bl[nt] = *(const bf16x8*)&w0tl[(size_t)col * 192 + koff];
            }
#pragma unroll
            for (int rt = 0; rt < 4; ++rt) {
                const bf16x8 Ah = *(const bf16x8*)&XH[rt * 16 + lr][ks * 32 + k0];
                const bf16x8 Al = *(const bf16x8*)&XL[rt * 16 + lr][ks * 32 + k0];
#pragma unroll
                for (int nt = 0; nt < 2; ++nt) {
                    acc[rt][nt] = __builtin_amdgcn_mfma_f32_16x16x32_bf16(Ah, Bh[nt], acc[rt][nt], 0, 0, 0);
                    acc[rt][nt] = __builtin_amdgcn_mfma_f32_16x16x32_bf16(Al, Bh[nt], acc[rt][nt], 0, 0, 0);
                    acc[rt][nt] = __builtin_amdgcn_mfma_f32_16x16x32_bf16(Ah, Bl[nt], acc[rt][nt], 0, 0, 0);
                }
            }
        }
    }
    __syncthreads();
#pragma unroll
    for (int rt = 0; rt < 4; ++rt)
#pragma unroll
        for (int nt = 0; nt < 2; ++nt)
#pragma unroll
            for (int r = 0; r < 4; ++r) {
                const int row = rt * 16 + 4 * lg + r;
                const int col = wbase + nt * 16 + lr;
                const float v = fmaxf(acc[rt][nt][r] + bias0[nt], 0.f);
                const short hi = to_bf(v);
                HH[row][col] = hi;
                HL[row][col] = to_bf(v - bf2f(hi));
            }
    __syncthreads();

    const int cbase = w * 16;
    const float bias1 = rb1[cbase + lr];
    f32x4 acc2[4];
#pragma unroll
    for (int rt = 0; rt < 4; ++rt) acc2[rt] = (f32x4){0.f, 0.f, 0.f, 0.f};

#pragma unroll
    for (int ks = 0; ks < 4; ++ks) {
        const int koff = ks * 32 + k0;
        const int col  = cbase + lr;
        const bf16x8 Bh = *(const bf16x8*)&w1th[(size_t)col * 128 + koff];
        const bf16x8 Bl = *(const bf16x8*)&w1tl[(size_t)col * 128 + koff];
#pragma unroll
        for (int rt = 0; rt < 4; ++rt) {
            const bf16x8 Ah = *(const bf16x8*)&HH[rt * 16 + lr][koff];
            const bf16x8 Al = *(const bf16x8*)&HL[rt * 16 + lr][koff];
            acc2[rt] = __builtin_amdgcn_mfma_f32_16x16x32_bf16(Ah, Bh, acc2[rt], 0, 0, 0);
            acc2[rt] = __builtin_amdgcn_mfma_f32_16x16x32_bf16(Al, Bh, acc2[rt], 0, 0, 0);
            acc2[rt] = __builtin_amdgcn_mfma_f32_16x16x32_bf16(Ah, Bl, acc2[rt], 0, 0, 0);
        }
    }
#pragma unroll
    for (int rt = 0; rt < 4; ++rt)
#pragma unroll
        for (int r = 0; r < 4; ++r)
            h2T[cbase + lr][rt * 16 + 4 * lg + r] = fmaxf(acc2[rt][r] + bias1, 0.f);
    __syncthreads();

    if (w == 0) {
        const int b = b0i + lane;
        float l0 = rb2[0], l1 = 0.f, l2 = 0.f, l3 = 0.f;
#pragma unroll
        for (int j = 0; j < 16; ++j) {
            l0 = fmaf(h2T[j][lane],      rw2[j],      l0);
            l1 = fmaf(h2T[16 + j][lane], rw2[16 + j], l1);
            l2 = fmaf(h2T[32 + j][lane], rw2[32 + j], l2);
            l3 = fmaf(h2T[48 + j][lane], rw2[48 + j], l3);
        }
        const float logit = (l0 + l1) + (l2 + l3);

        const int er1 = endi[b];
        const int er0 = (b == 0) ? 0 : endi[b - 1];
        const int ea1 = endi[NB + b];
        const int ea0 = endi[NB + b - 1];
        const float x0 = sqrtf((float)(ea1 - ea0));
        const float x1 = sqrtf((float)(er1 - er0));

        float t5[5];
#pragma unroll
        for (int m = 0; m < 5; ++m)
            t5[m] = fmaxf(cb0[m] + x0 * cw0[m] + x1 * cw0[5 + m], 0.f);
        float t5b[5];
#pragma unroll
        for (int m = 0; m < 5; ++m) {
            float v = cb1[m];
#pragma unroll
            for (int i = 0; i < 5; ++i) v = fmaf(t5[i], cw1[i * 5 + m], v);
            t5b[m] = fmaxf(v, 0.f);
        }
        float temp = cb2[0];
#pragma unroll
        for (int m = 0; m < 5; ++m) temp = fmaf(t5b[m], cw2[m], temp);

        const float ml = max_logit[0];
        out[b] = ml * tanhf((logit * temp) / ml);
    }
}

// ---------------------------------------------------------------------------
extern "C" void kernel_launch(void* const* d_in, const int* in_sizes, int n_in,
                              void* d_out, int out_size, void* d_ws, size_t ws_size,
                              hipStream_t stream)
{
    const float* reads  = (const float*)d_in[0];
    const float* info   = (const float*)d_in[1];
    const int*   endi   = (const int*)d_in[2];       // int64 inputs arrive as int32
    const float* phi_w0 = (const float*)d_in[3];
    const float* phi_b0 = (const float*)d_in[4];
    const float* phi_w1 = (const float*)d_in[5];
    const float* phi_b1 = (const float*)d_in[6];
    const float* om_w0  = (const float*)d_in[7];
    const float* om_b0  = (const float*)d_in[8];
    const float* om_w1  = (const float*)d_in[9];
    const float* om_b1  = (const float*)d_in[10];
    const float* rw0    = (const float*)d_in[11];
    const float* rb0    = (const float*)d_in[12];
    const float* rw1    = (const float*)d_in[13];
    const float* rb1    = (const float*)d_in[14];
    const float* rw2    = (const float*)d_in[15];
    const float* rb2    = (const float*)d_in[16];
    const float* cw0    = (const float*)d_in[17];
    const float* cb0    = (const float*)d_in[18];
    const float* cw1    = (const float*)d_in[19];
    const float* cb1    = (const float*)d_in[20];
    const float* cw2    = (const float*)d_in[21];
    const float* cb2    = (const float*)d_in[22];
    const float* mlog   = (const float*)d_in[23];

    char* ws = (char*)d_ws;
    float* means = (float*)ws;                                   // 16,777,216 B
    float* om    = (float*)(ws + 16777216);                      //  8,388,608 B
    short* w0th  = (short*)(ws + 25165824);                      //     49,152 B
    short* w0tl  = (short*)(ws + 25165824 + 49152);              //     49,152 B
    short* w1th  = (short*)(ws + 25165824 + 98304);              //     16,384 B
    short* w1tl  = (short*)(ws + 25165824 + 114688);             //     16,384 B
    short* p_w0t = (short*)(ws + 25165824 + 131072);             //      2,048 B
    short* p_w1t = (short*)(ws + 25165824 + 133120);             //      8,192 B
    float* out   = (float*)d_out;

    // K0: one-time weight prep
    hipLaunchKernelGGL(k0_prep, dim3(96), dim3(256), 0, stream,
                       rw0, rw1, phi_w0, phi_w1,
                       w0th, w0tl, w1th, w1tl, p_w0t, p_w1t);
    // K12 fused: 4096 phi blocks (dual-chain @ 256-reg budget) + 1024 omega
    hipLaunchKernelGGL(k12_fused, dim3(K1_BLOCKS + 1024), dim3(256), 0, stream,
                       reads, endi, p_w0t, p_w1t, phi_b0, phi_b1, means,
                       info, om_w0, om_b0, om_w1, om_b1, om);
    // K3: 64 rows per block -> 512 blocks x 256 threads
    hipLaunchKernelGGL(k3_rho_mfma, dim3(512), dim3(256), 0, stream,
                       means, om, endi, w0th, w0tl, w1th, w1tl,
                       rb0, rb1, rw2, rb2,
                       cw0, cb0, cw1, cb1, cw2, cb2, mlog, out);
}

// Round 23
// 91.825 us; speedup vs baseline: 1.1430x; 1.1430x over previous
//
#include <hip/hip_runtime.h>
#include <hip/hip_bf16.h>
#include <math.h>

#define NB 32768          // B
#define NSEG 65536        // 2*B
#define NRF 11            // read features
#define NIF 9             // info features
#define K1_BLOCKS 4096    // phi blocks in the fused dispatch

typedef __attribute__((ext_vector_type(8))) short bf16x8;
typedef __attribute__((ext_vector_type(4))) float f32x4;
typedef __attribute__((ext_vector_type(4))) unsigned u32x4;

__device__ __forceinline__ short to_bf(float f) {
    __hip_bfloat16 h = __float2bfloat16(f);   // RNE
    return *reinterpret_cast<short*>(&h);
}
__device__ __forceinline__ float bf2f(short s) {
    __hip_bfloat16 h = *reinterpret_cast<__hip_bfloat16*>(&s);
    return __bfloat162float(h);
}
// HW packed f32->bf16 RNE: lo -> D[15:0], hi -> D[31:16].
__device__ __forceinline__ unsigned cvt_pk_bf16(float lo, float hi) {
    unsigned r;
    asm("v_cvt_pk_bf16_f32 %0, %1, %2" : "=v"(r) : "v"(lo), "v"(hi));
    return r;
}

// ---------------------------------------------------------------------------
// K0: one-time weight prep into ws.
// p_w1t stores W1T with hidden-dim permutation sigma so K1's layer-1 output
// registers ARE the layer-2 A-fragment:
//   k' = 32c + 8lg + e  ->  sigma = 32c + 16(e>>2) + 4lg + (e&3)
// ---------------------------------------------------------------------------
__global__ __launch_bounds__(256) void k0_prep(
    const float* __restrict__ rw0, const float* __restrict__ rw1,
    const float* __restrict__ pw0, const float* __restrict__ pw1,
    short* __restrict__ w0th, short* __restrict__ w0tl,
    short* __restrict__ w1th, short* __restrict__ w1tl,
    short* __restrict__ p_w0t, short* __restrict__ p_w1t)
{
    const int idx = blockIdx.x * 256 + threadIdx.x;
    if (idx < 192 * 128) {
        const int k = idx >> 7, col = idx & 127;      // rw0[k][col]
        const float v = rw0[idx];
        const short hi = to_bf(v);
        const short lo = to_bf(v - bf2f(hi));
        w0th[col * 192 + k] = hi;
        w0tl[col * 192 + k] = lo;
    }
    if (idx < 128 * 64) {
        const int k = idx >> 6, col = idx & 63;       // rw1[k][col]
        const float v = rw1[idx];
        const short hi = to_bf(v);
        const short lo = to_bf(v - bf2f(hi));
        w1th[col * 128 + k] = hi;
        w1tl[col * 128 + k] = lo;
    }
    if (idx < 64 * 16) {
        const int col = idx >> 4, k = idx & 15;
        p_w0t[idx] = (k < NRF) ? to_bf(pw0[k * 64 + col]) : (short)0;
    }
    if (idx < 64 * 64) {
        const int col = idx >> 6, kp = idx & 63;
        const int c = kp >> 5, rem = kp & 31;
        const int lgi = rem >> 3, e = rem & 7;
        const int k = 32 * c + 16 * (e >> 2) + 4 * lgi + (e & 3);  // sigma(kp)
        p_w1t[idx] = to_bf(pw1[k * 64 + col]);
    }
}

// ---------------------------------------------------------------------------
// X-fragment load straight from global, segment-clamped row.
// ---------------------------------------------------------------------------
__device__ __forceinline__ bf16x8 load_xfrag(
    const float* __restrict__ reads, int e0v, int cnt, int tt, int lr, int lg)
{
    int rrow = tt * 16 + lr;
    rrow = (rrow < cnt) ? rrow : (cnt - 1);
    const size_t gbase = (size_t)(e0v + rrow) * NRF;
    bf16x8 xb = {0, 0, 0, 0, 0, 0, 0, 0};
    if (lg == 0) {
        const f32x4 x0 = *(const f32x4*)(reads + gbase);
        const f32x4 x1 = *(const f32x4*)(reads + gbase + 4);
        union { u32x4 u; bf16x8 s; } t;
        t.u = (u32x4){ cvt_pk_bf16(x0[0], x0[1]), cvt_pk_bf16(x0[2], x0[3]),
                       cvt_pk_bf16(x1[0], x1[1]), cvt_pk_bf16(x1[2], x1[3]) };
        xb = t.s;
    } else if (lg == 1) {
        const float xa = reads[gbase + 8];
        const float xbv = reads[gbase + 9];
        const float xc = reads[gbase + 10];
        union { u32x4 u; bf16x8 s; } t;
        t.u = (u32x4){ cvt_pk_bf16(xa, xbv), cvt_pk_bf16(xc, 0.f), 0u, 0u };
        xb = t.s;
    }
    return xb;
}

// ---------------------------------------------------------------------------
// K12 fused (round-17 winner, final): blocks < K1_BLOCKS run the v11 phi
// body (zero LDS, depth-2 prefetch, 16 segs/block); blocks >= K1_BLOCKS run
// the proven K2 omega body. K1 and K2 are data-independent, so fusing
// removes K2's serial latency.
// ---------------------------------------------------------------------------
__global__ __launch_bounds__(256, 4) void k12_fused(
    const float* __restrict__ reads,
    const int* __restrict__ endi,
    const short* __restrict__ p_w0t, const short* __restrict__ p_w1t,
    const float* __restrict__ b0, const float* __restrict__ b1,
    float* __restrict__ means,
    const float* __restrict__ info,
    const float* __restrict__ ow0, const float* __restrict__ ob0,
    const float* __restrict__ ow1, const float* __restrict__ ob1,
    float* __restrict__ om)
{
    __shared__ float hbuf[4][64];     // used by the K2 path only (1 KB)

    const int tid  = threadIdx.x;
    const int lane = tid & 63;
    const int w    = tid >> 6;

    if (blockIdx.x < K1_BLOCKS) {
        // ================== phi body (v11, unchanged) =======================
        const int lg   = lane >> 4;       // 0..3
        const int lr   = lane & 15;       // 0..15
        const int k0   = lg * 8;
        const int s0   = blockIdx.x * 16;

        bf16x8 aW0[4];
#pragma unroll
        for (int nt = 0; nt < 4; ++nt) {
            bf16x8 z = {0, 0, 0, 0, 0, 0, 0, 0};
            if (lg < 2) z = *(const bf16x8*)&p_w0t[(nt * 16 + lr) * 16 + k0];
            aW0[nt] = z;
        }
        bf16x8 bW1[4][2];
#pragma unroll
        for (int nt = 0; nt < 4; ++nt)
#pragma unroll
            for (int ks = 0; ks < 2; ++ks)
                bW1[nt][ks] = *(const bf16x8*)&p_w1t[(nt * 16 + lr) * 64 + ks * 32 + k0];

        f32x4 cbias0[4];
#pragma unroll
        for (int nt = 0; nt < 4; ++nt)
#pragma unroll
            for (int q = 0; q < 4; ++q) cbias0[nt][q] = b0[nt * 16 + 4 * lg + q];
        f32x4 cbias1[4];
#pragma unroll
        for (int nt = 0; nt < 4; ++nt) {
            const float bv = b1[nt * 16 + lr];
#pragma unroll
            for (int q = 0; q < 4; ++q) cbias1[nt][q] = bv;
        }

        for (int q = 0; q < 4; ++q) {
            const int sidx = s0 + q * 4 + w;
            const int e1   = endi[sidx];
            const int e0v  = (sidx == 0) ? 0 : endi[sidx - 1];
            const int cnt  = e1 - e0v;
            const int ntl  = (cnt + 15) >> 4;
            float segsum[4] = {0.f, 0.f, 0.f, 0.f};

            bf16x8 xb = load_xfrag(reads, e0v, cnt, 0, lr, lg);

            for (int tt = 0; tt < ntl; ++tt) {
                bf16x8 xbn = {0, 0, 0, 0, 0, 0, 0, 0};
                if (tt + 1 < ntl) xbn = load_xfrag(reads, e0v, cnt, tt + 1, lr, lg);

                f32x4 d[4];
#pragma unroll
                for (int nt = 0; nt < 4; ++nt)
                    d[nt] = __builtin_amdgcn_mfma_f32_16x16x32_bf16(aW0[nt], xb, cbias0[nt], 0, 0, 0);

                float h[4][4];
#pragma unroll
                for (int nt = 0; nt < 4; ++nt)
#pragma unroll
                    for (int q2 = 0; q2 < 4; ++q2) h[nt][q2] = fmaxf(d[nt][q2], 0.f);
                union { u32x4 u; bf16x8 s; } a2c0, a2c1;
                a2c0.u = (u32x4){ cvt_pk_bf16(h[0][0], h[0][1]),
                                  cvt_pk_bf16(h[0][2], h[0][3]),
                                  cvt_pk_bf16(h[1][0], h[1][1]),
                                  cvt_pk_bf16(h[1][2], h[1][3]) };
                a2c1.u = (u32x4){ cvt_pk_bf16(h[2][0], h[2][1]),
                                  cvt_pk_bf16(h[2][2], h[2][3]),
                                  cvt_pk_bf16(h[3][0], h[3][1]),
                                  cvt_pk_bf16(h[3][2], h[3][3]) };

                f32x4 o[4];
#pragma unroll
                for (int nt = 0; nt < 4; ++nt) {
                    f32x4 t = __builtin_amdgcn_mfma_f32_16x16x32_bf16(a2c0.s, bW1[nt][0], cbias1[nt], 0, 0, 0);
                    o[nt]   = __builtin_amdgcn_mfma_f32_16x16x32_bf16(a2c1.s, bW1[nt][1], t, 0, 0, 0);
                }
                const int rowg = tt * 16 + 4 * lg;
#pragma unroll
                for (int nt = 0; nt < 4; ++nt) {
                    float s = segsum[nt];
#pragma unroll
                    for (int q2 = 0; q2 < 4; ++q2) {
                        const float p = __builtin_amdgcn_rcpf(1.f + __expf(-o[nt][q2]));
                        s += (rowg + q2 < cnt) ? p : 0.f;
                    }
                    segsum[nt] = s;
                }
                xb = xbn;
            }
#pragma unroll
            for (int nt = 0; nt < 4; ++nt) {
                segsum[nt] += __shfl_xor(segsum[nt], 16);
                segsum[nt] += __shfl_xor(segsum[nt], 32);
            }
            if (lg == 0) {
                const float inv = 1.f / (float)cnt;
#pragma unroll
                for (int nt = 0; nt < 4; ++nt)
                    means[(size_t)sidx * 64 + nt * 16 + lr] = segsum[nt] * inv;
            }
        }
    } else {
        // ================== omega body (K2, unchanged) ======================
        const int wg = __builtin_amdgcn_readfirstlane(
            (int)((blockIdx.x - K1_BLOCKS) * 4 + w));

        float w0c[NIF];
#pragma unroll
        for (int k = 0; k < NIF; ++k) w0c[k] = ow0[k * 64 + lane];
        float w1c[64];
#pragma unroll
        for (int i = 0; i < 64; ++i) w1c[i] = ow1[i * 64 + lane];
        const float b0l = ob0[lane];
        const float b1l = ob1[lane];

        for (int i = 0; i < 8; ++i) {
            const int b = wg * 8 + i;
            const float* __restrict__ x = info + (size_t)b * NIF;
            float h = b0l;
#pragma unroll
            for (int k = 0; k < NIF; ++k) h = fmaf(x[k], w0c[k], h);
            h = fmaxf(h, 0.f);
            hbuf[w][lane] = h;
            float o = b1l;
            const float4* h4 = (const float4*)(&hbuf[w][0]);
#pragma unroll
            for (int q = 0; q < 16; ++q) {
                float4 hv = h4[q];
                o = fmaf(hv.x, w1c[4 * q + 0], o);
                o = fmaf(hv.y, w1c[4 * q + 1], o);
                o = fmaf(hv.z, w1c[4 * q + 2], o);
                o = fmaf(hv.w, w1c[4 * q + 3], o);
            }
            om[(size_t)b * 64 + lane] = 1.f / (1.f + __expf(-o));
        }
    }
}

// ---------------------------------------------------------------------------
// K3: rho MLP via split-bf16 MFMA (hh + lh + hl). (unchanged)
// ---------------------------------------------------------------------------
__global__ __launch_bounds__(256) void k3_rho_mfma(
    const float* __restrict__ means, const float* __restrict__ om,
    const int* __restrict__ endi,
    const short* __restrict__ w0th, const short* __restrict__ w0tl,
    const short* __restrict__ w1th, const short* __restrict__ w1tl,
    const float* __restrict__ rb0, const float* __restrict__ rb1,
    const float* __restrict__ rw2, const float* __restrict__ rb2,
    const float* __restrict__ cw0, const float* __restrict__ cb0,
    const float* __restrict__ cw1, const float* __restrict__ cb1,
    const float* __restrict__ cw2, const float* __restrict__ cb2,
    const float* __restrict__ max_logit,
    float* __restrict__ out)
{
    __shared__ __align__(16) char smemA[18432];
    __shared__ __align__(16) char smemB[34816];
    short (*XH)[72]  = (short(*)[72])smemA;
    short (*XL)[72]  = (short(*)[72])(smemA + 9216);
    short (*HH)[136] = (short(*)[136])smemB;
    short (*HL)[136] = (short(*)[136])(smemB + 17408);
    float (*h2T)[68] = (float(*)[68])smemA;

    const int tid  = threadIdx.x;
    const int lane = tid & 63;
    const int w    = tid >> 6;
    const int lg   = lane >> 4;
    const int lr   = lane & 15;
    const int k0   = lg * 8;
    const int b0i  = blockIdx.x * 64;

    const int wbase = w * 32;
    float bias0[2];
#pragma unroll
    for (int nt = 0; nt < 2; ++nt) bias0[nt] = rb0[wbase + nt * 16 + lr];

    f32x4 acc[4][2];
#pragma unroll
    for (int rt = 0; rt < 4; ++rt)
#pragma unroll
        for (int nt = 0; nt < 2; ++nt) acc[rt][nt] = (f32x4){0.f, 0.f, 0.f, 0.f};

    for (int c = 0; c < 3; ++c) {
        const float* __restrict__ src =
            (c == 0) ? means + (size_t)b0i * 64 :
            (c == 1) ? means + (size_t)(NB + b0i) * 64 :
                       om    + (size_t)b0i * 64;
        __syncthreads();
        for (int idx = tid; idx < 64 * 64; idx += 256) {
            const int row = idx >> 6, col = idx & 63;
            const float v = src[(size_t)row * 64 + col];
            const short hi = to_bf(v);
            const short lo = to_bf(v - bf2f(hi));
            XH[row][col] = hi;
            XL[row][col] = lo;
        }
        __syncthreads();

#pragma unroll
        for (int ks = 0; ks < 2; ++ks) {
            const int koff = c * 64 + ks * 32 + k0;
            bf16x8 Bh[2], Bl[2];
#pragma unroll
            for (int nt = 0; nt < 2; ++nt) {
                const int col = wbase + nt * 16 + lr;
                Bh[nt] = *(const bf16x8*)&w0th[(size_t)col * 192 + koff];
                Bl[nt] = *(const bf16x8*)&w0tl[(size_t)col * 192 + koff];
            }
#pragma unroll
            for (int rt = 0; rt < 4; ++rt) {
                const bf16x8 Ah = *(const bf16x8*)&XH[rt * 16 + lr][ks * 32 + k0];
                const bf16x8 Al = *(const bf16x8*)&XL[rt * 16 + lr][ks * 32 + k0];
#pragma unroll
                for (int nt = 0; nt < 2; ++nt) {
                    acc[rt][nt] = __builtin_amdgcn_mfma_f32_16x16x32_bf16(Ah, Bh[nt], acc[rt][nt], 0, 0, 0);
                    acc[rt][nt] = __builtin_amdgcn_mfma_f32_16x16x32_bf16(Al, Bh[nt], acc[rt][nt], 0, 0, 0);
                    acc[rt][nt] = __builtin_amdgcn_mfma_f32_16x16x32_bf16(Ah, Bl[nt], acc[rt][nt], 0, 0, 0);
                }
            }
        }
    }
    __syncthreads();
#pragma unroll
    for (int rt = 0; rt < 4; ++rt)
#pragma unroll
        for (int nt = 0; nt < 2; ++nt)
#pragma unroll
            for (int r = 0; r < 4; ++r) {
                const int row = rt * 16 + 4 * lg + r;
                const int col = wbase + nt * 16 + lr;
                const float v = fmaxf(acc[rt][nt][r] + bias0[nt], 0.f);
                const short hi = to_bf(v);
                HH[row][col] = hi;
                HL[row][col] = to_bf(v - bf2f(hi));
            }
    __syncthreads();

    const int cbase = w * 16;
    const float bias1 = rb1[cbase + lr];
    f32x4 acc2[4];
#pragma unroll
    for (int rt = 0; rt < 4; ++rt) acc2[rt] = (f32x4){0.f, 0.f, 0.f, 0.f};

#pragma unroll
    for (int ks = 0; ks < 4; ++ks) {
        const int koff = ks * 32 + k0;
        const int col  = cbase + lr;
        const bf16x8 Bh = *(const bf16x8*)&w1th[(size_t)col * 128 + koff];
        const bf16x8 Bl = *(const bf16x8*)&w1tl[(size_t)col * 128 + koff];
#pragma unroll
        for (int rt = 0; rt < 4; ++rt) {
            const bf16x8 Ah = *(const bf16x8*)&HH[rt * 16 + lr][koff];
            const bf16x8 Al = *(const bf16x8*)&HL[rt * 16 + lr][koff];
            acc2[rt] = __builtin_amdgcn_mfma_f32_16x16x32_bf16(Ah, Bh, acc2[rt], 0, 0, 0);
            acc2[rt] = __builtin_amdgcn_mfma_f32_16x16x32_bf16(Al, Bh, acc2[rt], 0, 0, 0);
            acc2[rt] = __builtin_amdgcn_mfma_f32_16x16x32_bf16(Ah, Bl, acc2[rt], 0, 0, 0);
        }
    }
#pragma unroll
    for (int rt = 0; rt < 4; ++rt)
#pragma unroll
        for (int r = 0; r < 4; ++r)
            h2T[cbase + lr][rt * 16 + 4 * lg + r] = fmaxf(acc2[rt][r] + bias1, 0.f);
    __syncthreads();

    if (w == 0) {
        const int b = b0i + lane;
        float l0 = rb2[0], l1 = 0.f, l2 = 0.f, l3 = 0.f;
#pragma unroll
        for (int j = 0; j < 16; ++j) {
            l0 = fmaf(h2T[j][lane],      rw2[j],      l0);
            l1 = fmaf(h2T[16 + j][lane], rw2[16 + j], l1);
            l2 = fmaf(h2T[32 + j][lane], rw2[32 + j], l2);
            l3 = fmaf(h2T[48 + j][lane], rw2[48 + j], l3);
        }
        const float logit = (l0 + l1) + (l2 + l3);

        const int er1 = endi[b];
        const int er0 = (b == 0) ? 0 : endi[b - 1];
        const int ea1 = endi[NB + b];
        const int ea0 = endi[NB + b - 1];
        const float x0 = sqrtf((float)(ea1 - ea0));
        const float x1 = sqrtf((float)(er1 - er0));

        float t5[5];
#pragma unroll
        for (int m = 0; m < 5; ++m)
            t5[m] = fmaxf(cb0[m] + x0 * cw0[m] + x1 * cw0[5 + m], 0.f);
        float t5b[5];
#pragma unroll
        for (int m = 0; m < 5; ++m) {
            float v = cb1[m];
#pragma unroll
            for (int i = 0; i < 5; ++i) v = fmaf(t5[i], cw1[i * 5 + m], v);
            t5b[m] = fmaxf(v, 0.f);
        }
        float temp = cb2[0];
#pragma unroll
        for (int m = 0; m < 5; ++m) temp = fmaf(t5b[m], cw2[m], temp);

        const float ml = max_logit[0];
        out[b] = ml * tanhf((logit * temp) / ml);
    }
}

// ---------------------------------------------------------------------------
extern "C" void kernel_launch(void* const* d_in, const int* in_sizes, int n_in,
                              void* d_out, int out_size, void* d_ws, size_t ws_size,
                              hipStream_t stream)
{
    const float* reads  = (const float*)d_in[0];
    const float* info   = (const float*)d_in[1];
    const int*   endi   = (const int*)d_in[2];       // int64 inputs arrive as int32
    const float* phi_w0 = (const float*)d_in[3];
    const float* phi_b0 = (const float*)d_in[4];
    const float* phi_w1 = (const float*)d_in[5];
    const float* phi_b1 = (const float*)d_in[6];
    const float* om_w0  = (const float*)d_in[7];
    const float* om_b0  = (const float*)d_in[8];
    const float* om_w1  = (const float*)d_in[9];
    const float* om_b1  = (const float*)d_in[10];
    const float* rw0    = (const float*)d_in[11];
    const float* rb0    = (const float*)d_in[12];
    const float* rw1    = (const float*)d_in[13];
    const float* rb1    = (const float*)d_in[14];
    const float* rw2    = (const float*)d_in[15];
    const float* rb2    = (const float*)d_in[16];
    const float* cw0    = (const float*)d_in[17];
    const float* cb0    = (const float*)d_in[18];
    const float* cw1    = (const float*)d_in[19];
    const float* cb1    = (const float*)d_in[20];
    const float* cw2    = (const float*)d_in[21];
    const float* cb2    = (const float*)d_in[22];
    const float* mlog   = (const float*)d_in[23];

    char* ws = (char*)d_ws;
    float* means = (float*)ws;                                   // 16,777,216 B
    float* om    = (float*)(ws + 16777216);                      //  8,388,608 B
    short* w0th  = (short*)(ws + 25165824);                      //     49,152 B
    short* w0tl  = (short*)(ws + 25165824 + 49152);              //     49,152 B
    short* w1th  = (short*)(ws + 25165824 + 98304);              //     16,384 B
    short* w1tl  = (short*)(ws + 25165824 + 114688);             //     16,384 B
    short* p_w0t = (short*)(ws + 25165824 + 131072);             //      2,048 B
    short* p_w1t = (short*)(ws + 25165824 + 133120);             //      8,192 B
    float* out   = (float*)d_out;

    // K0: one-time weight prep
    hipLaunchKernelGGL(k0_prep, dim3(96), dim3(256), 0, stream,
                       rw0, rw1, phi_w0, phi_w1,
                       w0th, w0tl, w1th, w1tl, p_w0t, p_w1t);
    // K12 fused: 4096 phi blocks + 1024 omega blocks in one dispatch
    hipLaunchKernelGGL(k12_fused, dim3(K1_BLOCKS + 1024), dim3(256), 0, stream,
                       reads, endi, p_w0t, p_w1t, phi_b0, phi_b1, means,
                       info, om_w0, om_b0, om_w1, om_b1, om);
    // K3: 64 rows per block -> 512 blocks x 256 threads
    hipLaunchKernelGGL(k3_rho_mfma, dim3(512), dim3(256), 0, stream,
                       means, om, endi, w0th, w0tl, w1th, w1tl,
                       rb0, rb1, rw2, rb2,
                       cw0, cb0, cw1, cb1, cw2, cb2, mlog, out);
}